// Round 1
// 323.376 us; speedup vs baseline: 1.1480x; 1.1480x over previous
//
#include <hip/hip_runtime.h>
#include <math.h>

// Keep box arithmetic bit-identical to numpy fp32 (no fma contraction):
// matching decisions (iou > 0.5, argmax) must not flip.
#pragma clang fp contract(off)

#define BB 64
#define AA 8732
#define CC 81
#define GG 32
#define A_BLOCKS 35                // ceil(8732/256)
#define KA1_BLOCKS (BB*A_BLOCKS)   // 2240
#define KA2_BLOCKS (BB*GG/4)       // 512
#define ROWS_PC 64                 // conf rows per kC chunk
#define KC_BLOCKS (BB*AA/ROWS_PC)  // 8732 chunks, exact
#define CHUNK_F4 (ROWS_PC*81/4)    // 1296 float4 per chunk, exact

// ---- workspace layout (bytes) ----
// [0,8192)            bestp  u32[B*G]
// [8192,567040)       bestg  u8[B*A]
// [567040,2802432)    cls_l  f32[B*A]
// [2802432,2802436)   ticket u32        (zeroed by kAC block 0)
// [2802440,2802448)   btot_acc double   (zeroed by kAC block 0)
// [2802448,2802452)   np_acc int        (zeroed by kAC block 0)

// ---------------- Kernel AC: one dispatch, three roles ----------------
// blocks [0,2240):        kA1 — per-anchor best gt (thread per anchor)
// blocks [2240,2752):     kA2 — per-gt best anchor (wave per (b,g))
// blocks [2752,2752+8732) kC  — conf logsumexp, LDS-staged coalesced stream:
//   stage 64 rows (20736 B) with fully-coalesced float4 loads, then 4
//   threads/row sum exp(class) from LDS and combine with shfl_xor.
// iou compare by cross-multiplication: iou1>iou2 <=> i1*u2 > i2*u1 (all >0);
// threshold iou>0.5 <=> 2*i > u. No division anywhere.
__global__ __launch_bounds__(256) void kAC(const float* __restrict__ anchors,
    const float* __restrict__ gt_boxes, const float* __restrict__ conf,
    unsigned char* __restrict__ bestg, unsigned int* __restrict__ bestp,
    float* __restrict__ cls_l, unsigned int* __restrict__ ticket,
    double* __restrict__ btot_acc, int* __restrict__ np_acc)
{
    __shared__ float buf[ROWS_PC * 81];          // 20736 B
    int tid = threadIdx.x;
    if (blockIdx.x == 0 && tid == 0) {           // init for kBDE's final reduce
        *ticket = 0u; *btot_acc = 0.0; *np_acc = 0;
    }
    if (blockIdx.x < KA1_BLOCKS) {
        int blk = blockIdx.x;
        int b = blk / A_BLOCKS, ca = blk % A_BLOCKS;
        int a = ca * 256 + tid;
        float4* gco = (float4*)buf;              // overlay: 32 float4
        float* gar = buf + GG * 4;               // overlay: 32 floats
        if (tid < GG) {
            float4 gb = ((const float4*)gt_boxes)[b * GG + tid];
            float x1 = gb.x - gb.z / 2.0f, y1 = gb.y - gb.w / 2.0f;
            float x2 = gb.x + gb.z / 2.0f, y2 = gb.y + gb.w / 2.0f;
            gco[tid] = make_float4(x1, y1, x2, y2);
            gar[tid] = (x2 - x1) * (y2 - y1);    // same rounding as reference
        }
        __syncthreads();
        if (a >= AA) return;
        float4 an = ((const float4*)anchors)[a];
        float ax1 = an.x - an.z / 2.0f, ay1 = an.y - an.w / 2.0f;
        float ax2 = an.x + an.z / 2.0f, ay2 = an.y + an.w / 2.0f;
        float aar = (ax2 - ax1) * (ay2 - ay1);
        float bi = -1.0f, bu = 1.0f; int bgi = 0;   // first compare takes g=0
#pragma unroll
        for (int g = 0; g < GG; ++g) {
            float4 c = gco[g];
            float ltx = fmaxf(c.x, ax1), lty = fmaxf(c.y, ay1);
            float rbx = fminf(c.z, ax2), rby = fminf(c.w, ay2);
            float w = fmaxf(rbx - ltx, 0.0f), h = fmaxf(rby - lty, 0.0f);
            float inter = w * h;
            float uni = gar[g] + aar - inter;
            if (inter * bu > bi * uni) { bi = inter; bu = uni; bgi = g; }  // strict >: first max
        }
        bestg[b * AA + a] = (2.0f * bi > bu) ? (unsigned char)bgi : (unsigned char)0xFF;
    } else if (blockIdx.x < KA1_BLOCKS + KA2_BLOCKS) {
        int wv = tid >> 6, lane = tid & 63;
        int pair = (blockIdx.x - KA1_BLOCKS) * 4 + wv;   // 0..2047
        int b = pair >> 5, g = pair & 31;
        float4 gb = ((const float4*)gt_boxes)[b * GG + g];
        float gx1 = gb.x - gb.z / 2.0f, gy1 = gb.y - gb.w / 2.0f;
        float gx2 = gb.x + gb.z / 2.0f, gy2 = gb.y + gb.w / 2.0f;
        float gar2 = (gx2 - gx1) * (gy2 - gy1);
        float bi = -1.0f, bu = 1.0f; int ba = 0;
        for (int a = lane; a < AA; a += 64) {
            float4 an = ((const float4*)anchors)[a];
            float ax1 = an.x - an.z / 2.0f, ay1 = an.y - an.w / 2.0f;
            float ax2 = an.x + an.z / 2.0f, ay2 = an.y + an.w / 2.0f;
            float aar = (ax2 - ax1) * (ay2 - ay1);
            float ltx = fmaxf(gx1, ax1), lty = fmaxf(gy1, ay1);
            float rbx = fminf(gx2, ax2), rby = fminf(gy2, ay2);
            float w = fmaxf(rbx - ltx, 0.0f), h = fmaxf(rby - lty, 0.0f);
            float inter = w * h;
            float uni = gar2 + aar - inter;
            if (inter * bu > bi * uni) { bi = inter; bu = uni; ba = a; }  // smallest a in stream
        }
        // wave butterfly-reduce, lexicographic (iou desc, a asc)
#pragma unroll
        for (int off = 32; off > 0; off >>= 1) {
            float oi = __shfl_down(bi, off);
            float ou = __shfl_down(bu, off);
            int   oa = __shfl_down(ba, off);
            float p1 = oi * bu, p2 = bi * ou;
            bool take = (p1 > p2) || ((p1 == p2) && (oa < ba));
            if (take) { bi = oi; bu = ou; ba = oa; }
        }
        if (lane == 0) bestp[pair] = (unsigned int)ba;
    } else {
        int chunk = blockIdx.x - KA1_BLOCKS - KA2_BLOCKS;   // 0..8731
        const float4* __restrict__ src4 = (const float4*)conf;
        size_t base4 = (size_t)chunk * CHUNK_F4;
        float4* buf4 = (float4*)buf;
#pragma unroll
        for (int i = 0; i < 5; ++i) buf4[tid + 256 * i] = src4[base4 + tid + 256 * i];
        if (tid < CHUNK_F4 - 1280) buf4[1280 + tid] = src4[base4 + 1280 + tid];
        __syncthreads();
        int r = tid >> 2, q = tid & 3;           // 4 threads per row
        const float* row = buf + r * 81;
        int kstart = (q == 0) ? 0 : 21 + (q - 1) * 20;   // 21/20/20/20 split
        float s = 0.0f;
#pragma unroll
        for (int k = 0; k < 20; ++k) s += __expf(row[kstart + k]);
        if (q == 0) s += __expf(row[20]);
        s += __shfl_xor(s, 1);
        s += __shfl_xor(s, 2);
        if (q == 0)
            cls_l[chunk * ROWS_PC + r] = __logf(s) - row[0];  // idx01=0 for negatives
    }
}

// ---------------- Kernel BDE: fused finalize + radix top-k + final reduce ----------------
// One block per batch image, 1024 threads (4x MLP/scan parallelism vs 256).
// labels live only in LDS (global label array deleted). cl[] reuses forced[]'s
// LDS space (phase-separated by __syncthreads). Radix histogram is privatized
// per wave (16x256) to avoid same-address LDS-atomic serialization in pass 1
// (nearly all values share the same exponent byte).
__global__ __launch_bounds__(1024) void kBDE(const float* __restrict__ anchors,
    const float* __restrict__ gt_boxes, const int* __restrict__ gt_labels,
    const float* __restrict__ loc_pred, const unsigned char* __restrict__ bestg,
    const unsigned int* __restrict__ bestp, const float* __restrict__ cls_l,
    const float* __restrict__ conf, unsigned int* __restrict__ ticket,
    double* __restrict__ btot_acc, int* __restrict__ np_acc,
    float* __restrict__ out)
{
    int b = blockIdx.x, tid = threadIdx.x;
    __shared__ int forced[AA];                   // 34928 B; becomes cl[] in phase 2
    __shared__ unsigned char slab[AA];           // 8732 B labels
    __shared__ unsigned int whist[16 * 256];     // 16384 B per-wave histograms
    __shared__ unsigned int hist[256];
    __shared__ float gcx[GG], gcy[GG], gw[GG], gh[GG];
    __shared__ int glab[GG];
    __shared__ double red_d[16];
    __shared__ int red_i[16];
    __shared__ unsigned int red_u[16];
    __shared__ unsigned int sh_prefix, sh_remaining;
    __shared__ int sh_np;
    __shared__ double sh_loc;
    unsigned int* cl = (unsigned int*)forced;

    for (int i = tid; i < AA; i += 1024) forced[i] = -1;
    if (tid < GG) {
        float4 gb = ((const float4*)gt_boxes)[b * GG + tid];
        gcx[tid] = gb.x; gcy[tid] = gb.y; gw[tid] = gb.z; gh[tid] = gb.w;
        glab[tid] = gt_labels[b * GG + tid];
    }
    __syncthreads();
    if (tid < GG)
        atomicMax(&forced[(int)bestp[b * GG + tid]], tid);  // duplicates: largest g wins
    __syncthreads();

    // ---- phase 1: labels, positives, loc loss ----
    double lsum = 0.0; int pcount = 0;
    for (int a = tid; a < AA; a += 1024) {
        int gf = forced[a];
        int gsel;
        if (gf >= 0) gsel = gf;
        else {
            unsigned char bg = bestg[b * AA + a];
            gsel = (bg == 0xFF) ? -1 : (int)bg;
        }
        int lab = 0;
        if (gsel >= 0) {
            lab = glab[gsel];                    // labels in 1..C-1 -> positive
            float4 an = ((const float4*)anchors)[a];
            float e0 = (gcx[gsel] - an.x) / an.z;
            float e1 = (gcy[gsel] - an.y) / an.w;
            float e2 = logf(gw[gsel]) - logf(an.z);
            float e3 = logf(gh[gsel]) - logf(an.w);
            float4 lp = ((const float4*)loc_pred)[b * AA + a];
            float d0 = lp.x - e0, d1 = lp.y - e1, d2 = lp.z - e2, d3 = lp.w - e3;
            float t = 0.0f, ad;
            ad = fabsf(d0); t += (ad < 1.0f) ? 0.5f * d0 * d0 : ad - 0.5f;
            ad = fabsf(d1); t += (ad < 1.0f) ? 0.5f * d1 * d1 : ad - 0.5f;
            ad = fabsf(d2); t += (ad < 1.0f) ? 0.5f * d2 * d2 : ad - 0.5f;
            ad = fabsf(d3); t += (ad < 1.0f) ? 0.5f * d3 * d3 : ad - 0.5f;
            lsum += (double)t;
            pcount++;
        }
        slab[a] = (unsigned char)lab;
    }
#pragma unroll
    for (int off = 32; off > 0; off >>= 1) {
        lsum += __shfl_down(lsum, off);
        pcount += __shfl_down(pcount, off);
    }
    if ((tid & 63) == 0) { red_d[tid >> 6] = lsum; red_i[tid >> 6] = pcount; }
    __syncthreads();                             // also fences forced[] reads before cl[] writes
    if (tid == 0) {
        double L = 0.0; int P = 0;
        for (int w = 0; w < 16; ++w) { L += red_d[w]; P += red_i[w]; }
        sh_loc = L; sh_np = P;
    }
    __syncthreads();
    int np_ = sh_np;

    // ---- phase 2: cl[] keys + positive CE ----
    double pc = 0.0;
    const float* src = cls_l + b * AA;
    for (int i = tid; i < AA; i += 1024) {
        int lab = slab[i];
        float sv = src[i];
        if (lab > 0) {
            size_t rowb = ((size_t)(b * AA + i)) * 81;
            pc += (double)(sv + conf[rowb] - conf[rowb + lab]);
            cl[i] = 0u;                          // positives excluded from neg mining
        } else {
            cl[i] = __float_as_uint(fmaxf(sv, 0.0f));  // guard tiny negative rounding
        }
    }
#pragma unroll
    for (int off = 32; off > 0; off >>= 1) pc += __shfl_down(pc, off);
    if ((tid & 63) == 0) red_d[tid >> 6] = pc;
    __syncthreads();
    double sum_pos = 0.0;
    int k = min(3 * np_, AA - 1);                // num_neg = min(3*num_pos, A-1)
    if (tid == 0) {
        for (int w = 0; w < 16; ++w) sum_pos += red_d[w];
        sh_prefix = 0u; sh_remaining = (unsigned int)k;
    }
    __syncthreads();

    double topk = 0.0;
    int p_t_pos = 0;                             // positives inside neg_mask (tie at 0)
    if (k > 0) {
        for (int shift = 24; shift >= 0; shift -= 8) {
            for (int j = tid; j < 4096; j += 1024) whist[j] = 0u;
            __syncthreads();
            unsigned int mask = (shift == 24) ? 0u : (0xFFFFFFFFu << (shift + 8));
            unsigned int pre = sh_prefix;
            unsigned int* myh = whist + (tid >> 6) * 256;
            for (int i = tid; i < AA; i += 1024) {
                unsigned int u = cl[i];
                if ((u & mask) == pre) atomicAdd(&myh[(u >> shift) & 255], 1u);
            }
            __syncthreads();
            if (tid < 256) {
                unsigned int t = 0;
#pragma unroll
                for (int w = 0; w < 16; ++w) t += whist[w * 256 + tid];
                hist[tid] = t;
            }
            __syncthreads();
            if (tid < 64) {                      // wave-parallel digit select
                int l = tid;
                unsigned int h4 = hist[4 * l] + hist[4 * l + 1]
                                + hist[4 * l + 2] + hist[4 * l + 3];
                unsigned int S = h4;             // suffix sum over lane groups
#pragma unroll
                for (int off = 1; off < 64; off <<= 1) {
                    unsigned int o = __shfl_down(S, off);
                    S += (l + off < 64) ? o : 0u;
                }
                unsigned int rem = sh_remaining;
                unsigned long long ball = __ballot(S >= rem);  // lanes 0..L set
                int L = 63 - __clzll(ball);
                if (l == L) {
                    unsigned int rem2 = rem - (S - h4);
                    unsigned int c = 0;
                    for (int dd = 4 * L + 3; dd >= 4 * L; --dd) {
                        c += hist[dd];
                        if (c >= rem2) {
                            sh_prefix = pre | ((unsigned int)dd << shift);
                            sh_remaining = rem2 - (c - hist[dd]);
                            break;
                        }
                    }
                }
            }
            __syncthreads();
        }
        unsigned int vbits = sh_prefix;
        unsigned int myc = 0; double mys = 0.0;
        for (int i = tid; i < AA; i += 1024) {
            unsigned int u = cl[i];
            if (u > vbits) { myc++; mys += (double)__uint_as_float(u); }
        }
#pragma unroll
        for (int off = 32; off > 0; off >>= 1) {
            myc += __shfl_down(myc, off);
            mys += __shfl_down(mys, off);
        }
        if ((tid & 63) == 0) { red_u[tid >> 6] = myc; red_d[tid >> 6] = mys; }
        __syncthreads();
        if (tid == 0) {
            unsigned int cnt_gt = 0; double sum_gt = 0.0;
            for (int w = 0; w < 16; ++w) { cnt_gt += red_u[w]; sum_gt += red_d[w]; }
            topk = sum_gt + (double)(k - (int)cnt_gt) * (double)__uint_as_float(vbits);
            if (vbits == 0u) {
                int t = k - (int)cnt_gt, c2 = 0;
                for (int i = 0; i < AA && c2 < t; ++i) {
                    if (cl[i] == 0u) { c2++; if (slab[i] > 0) p_t_pos++; }
                }
            }
        }
    }
    if (tid == 0) {
        int unsampled = AA - np_ - k + p_t_pos;
        double clsb = sum_pos + topk + (double)unsampled * (double)logf(81.0f);
        double myb = sh_loc + clsb;
        atomicAdd(btot_acc, myb);                // device-scope by default
        atomicAdd(np_acc, np_);
        __threadfence();
        unsigned int t = atomicAdd(ticket, 1u);
        if (t == BB - 1) {                       // last block: all adds happened-before
            double tt = atomicAdd(btot_acc, 0.0);   // returns old = full sum
            int nn = atomicAdd(np_acc, 0);
            out[0] = (float)(tt / (double)nn);
        }
    }
}

extern "C" void kernel_launch(void* const* d_in, const int* in_sizes, int n_in,
                              void* d_out, int out_size, void* d_ws, size_t ws_size,
                              hipStream_t stream) {
    (void)in_sizes; (void)n_in; (void)out_size; (void)ws_size;
    const float* loc_pred  = (const float*)d_in[0];
    const float* conf_pred = (const float*)d_in[1];
    const float* anchors   = (const float*)d_in[2];
    const float* gt_boxes  = (const float*)d_in[3];
    const int*   gt_labels = (const int*)d_in[4];

    char* ws = (char*)d_ws;
    unsigned int*  bestp    = (unsigned int*)(ws + 0);
    unsigned char* bestg    = (unsigned char*)(ws + 8192);
    float*         cls_l    = (float*)(ws + 567040);
    unsigned int*  ticket   = (unsigned int*)(ws + 2802432);
    double*        btot_acc = (double*)(ws + 2802440);
    int*           np_acc   = (int*)(ws + 2802448);

    kAC <<<KA1_BLOCKS + KA2_BLOCKS + KC_BLOCKS, 256, 0, stream>>>(
        anchors, gt_boxes, conf_pred, bestg, bestp, cls_l, ticket, btot_acc, np_acc);
    kBDE<<<BB, 1024, 0, stream>>>(anchors, gt_boxes, gt_labels, loc_pred,
        bestg, bestp, cls_l, conf_pred, ticket, btot_acc, np_acc, (float*)d_out);
}

// Round 2
// 323.161 us; speedup vs baseline: 1.1487x; 1.0007x over previous
//
#include <hip/hip_runtime.h>
#include <math.h>

// Keep box arithmetic bit-identical to numpy fp32 (no fma contraction):
// matching decisions (iou > 0.5, argmax) must not flip.
#pragma clang fp contract(off)

#define BB 64
#define AA 8732
#define CC 81
#define GG 32
#define A_BLOCKS 35                // ceil(8732/256)
#define KA1_BLOCKS (BB*A_BLOCKS)   // 2240
#define KA2_BLOCKS (BB*GG/4)       // 512
#define KA_BLOCKS (KA1_BLOCKS+KA2_BLOCKS)
#define ROWS_PC 64                 // conf rows per kC chunk
#define KC_CHUNKS (BB*AA/ROWS_PC)  // 8732 chunks, exact
#define CHUNK_F4 (ROWS_PC*81/4)    // 1296 float4 per chunk, exact
#define KC_GRID 768                // 3 blocks/CU at 41.5 KB LDS
#define KB_SEGS 8
#define KB_BLOCKS (BB*KB_SEGS)     // 512
#define SEGSZ 1092                 // 8*1092 >= 8732

// ---- workspace layout (bytes) ----
// [0,8192)            bestp   u32[B*G]
// [8192,567040)       bestg   u8[B*A]
// [567040,2802432)    cls_l   f32[B*A]
// [2802432,5037824)   keyg    u32[B*A]  radix keys
// [5037824,5596672)   labg    u8[B*A]
// [5596672,5596928)   num_pos i32[64]   (atomic, zeroed by kA blk0)
// [5596928,5597440)   loc_sum f64[64]   (atomic)
// [5597440,5597952)   cls_pos f64[64]   (atomic)
// [5597952,5597956)   ticket  u32
// [5597960,5597968)   btot    f64
// [5597968,5597972)   np_acc  i32

__device__ __forceinline__ void iou_upd(const float4 an, int a,
    float gx1, float gy1, float gx2, float gy2, float gar2,
    float& bi, float& bu, int& ba)
{
    float ax1 = an.x - an.z / 2.0f, ay1 = an.y - an.w / 2.0f;
    float ax2 = an.x + an.z / 2.0f, ay2 = an.y + an.w / 2.0f;
    float aar = (ax2 - ax1) * (ay2 - ay1);
    float ltx = fmaxf(gx1, ax1), lty = fmaxf(gy1, ay1);
    float rbx = fminf(gx2, ax2), rby = fminf(gy2, ay2);
    float w = fmaxf(rbx - ltx, 0.0f), h = fmaxf(rby - lty, 0.0f);
    float inter = w * h;
    float uni = gar2 + aar - inter;
    if (inter * bu > bi * uni) { bi = inter; bu = uni; ba = a; }  // strict >: first max
}

// ---------------- Kernel A: both matchings ----------------
// blocks [0,2240):    per-anchor best gt (thread per anchor)
// blocks [2240,2752): per-gt best anchor (wave per (b,g)), 4x-batched loads
__global__ __launch_bounds__(256) void kA(const float* __restrict__ anchors,
    const float* __restrict__ gt_boxes, unsigned char* __restrict__ bestg,
    unsigned int* __restrict__ bestp, int* __restrict__ num_pos,
    double* __restrict__ loc_sum, double* __restrict__ cls_pos,
    unsigned int* __restrict__ ticket, double* __restrict__ btot_acc,
    int* __restrict__ np_acc)
{
    int tid = threadIdx.x;
    if (blockIdx.x == 0) {                        // init accumulators for kB/kE
        if (tid < BB) { num_pos[tid] = 0; loc_sum[tid] = 0.0; cls_pos[tid] = 0.0; }
        if (tid == 0) { *ticket = 0u; *btot_acc = 0.0; *np_acc = 0; }
    }
    if (blockIdx.x < KA1_BLOCKS) {
        __shared__ float4 gco[GG];
        __shared__ float gar[GG];
        int blk = blockIdx.x;
        int b = blk / A_BLOCKS, ca = blk % A_BLOCKS;
        int a = ca * 256 + tid;
        if (tid < GG) {
            float4 gb = ((const float4*)gt_boxes)[b * GG + tid];
            float x1 = gb.x - gb.z / 2.0f, y1 = gb.y - gb.w / 2.0f;
            float x2 = gb.x + gb.z / 2.0f, y2 = gb.y + gb.w / 2.0f;
            gco[tid] = make_float4(x1, y1, x2, y2);
            gar[tid] = (x2 - x1) * (y2 - y1);     // same rounding as reference
        }
        __syncthreads();
        if (a >= AA) return;
        float4 an = ((const float4*)anchors)[a];
        float ax1 = an.x - an.z / 2.0f, ay1 = an.y - an.w / 2.0f;
        float ax2 = an.x + an.z / 2.0f, ay2 = an.y + an.w / 2.0f;
        float aar = (ax2 - ax1) * (ay2 - ay1);
        float bi = -1.0f, bu = 1.0f; int bgi = 0;
#pragma unroll
        for (int g = 0; g < GG; ++g) {
            float4 c = gco[g];
            float ltx = fmaxf(c.x, ax1), lty = fmaxf(c.y, ay1);
            float rbx = fminf(c.z, ax2), rby = fminf(c.w, ay2);
            float w = fmaxf(rbx - ltx, 0.0f), h = fmaxf(rby - lty, 0.0f);
            float inter = w * h;
            float uni = gar[g] + aar - inter;
            if (inter * bu > bi * uni) { bi = inter; bu = uni; bgi = g; }
        }
        bestg[b * AA + a] = (2.0f * bi > bu) ? (unsigned char)bgi : (unsigned char)0xFF;
    } else {
        int wv = tid >> 6, lane = tid & 63;
        int pair = (blockIdx.x - KA1_BLOCKS) * 4 + wv;   // 0..2047
        int b = pair >> 5, g = pair & 31;
        float4 gb = ((const float4*)gt_boxes)[b * GG + g];
        float gx1 = gb.x - gb.z / 2.0f, gy1 = gb.y - gb.w / 2.0f;
        float gx2 = gb.x + gb.z / 2.0f, gy2 = gb.y + gb.w / 2.0f;
        float gar2 = (gx2 - gx1) * (gy2 - gy1);
        const float4* __restrict__ A4 = (const float4*)anchors;
        float bi = -1.0f, bu = 1.0f; int ba = 0;
        // 8732 = 64*136 + 28; process a = lane + 64k ascending (preserves tie order)
        for (int k0 = 0; k0 < 136; k0 += 4) {
            int a0 = lane + 64 * k0;
            float4 v0 = A4[a0];                   // 4 independent loads in flight
            float4 v1 = A4[a0 + 64];
            float4 v2 = A4[a0 + 128];
            float4 v3 = A4[a0 + 192];
            iou_upd(v0, a0,       gx1, gy1, gx2, gy2, gar2, bi, bu, ba);
            iou_upd(v1, a0 + 64,  gx1, gy1, gx2, gy2, gar2, bi, bu, ba);
            iou_upd(v2, a0 + 128, gx1, gy1, gx2, gy2, gar2, bi, bu, ba);
            iou_upd(v3, a0 + 192, gx1, gy1, gx2, gy2, gar2, bi, bu, ba);
        }
        if (lane < 28) {                          // tail: a = 8704..8731
            int a = 8704 + lane;
            iou_upd(A4[a], a, gx1, gy1, gx2, gy2, gar2, bi, bu, ba);
        }
        // wave butterfly-reduce, lexicographic (iou desc, a asc)
#pragma unroll
        for (int off = 32; off > 0; off >>= 1) {
            float oi = __shfl_down(bi, off);
            float ou = __shfl_down(bu, off);
            int   oa = __shfl_down(ba, off);
            float p1 = oi * bu, p2 = bi * ou;
            bool take = (p1 > p2) || ((p1 == p2) && (oa < ba));
            if (take) { bi = oi; bu = ou; ba = oa; }
        }
        if (lane == 0) bestp[pair] = (unsigned int)ba;
    }
}

// ---------------- Kernel C: conf logsumexp, double-buffered grid-stride ----------------
// 768 blocks x ~11 chunks of 64 rows. Per iter: barrier -> issue next-chunk
// loads (regs) -> compute current from LDS -> ds_write next. The syncthreads
// vmcnt drain costs nothing (all prior loads already consumed); the new loads
// live across the whole compute phase -> continuous outstanding reads.
__global__ __launch_bounds__(256) void kC(const float* __restrict__ conf,
    float* __restrict__ cls_l)
{
    __shared__ float buf[2][ROWS_PC * 81];        // 2 x 20736 B
    int tid = threadIdx.x;
    const float4* __restrict__ src4 = (const float4*)conf;
    float4 r0, r1, r2, r3, r4, r5;
    int chunk = blockIdx.x;
    {   // prologue: stage chunk0 -> buf[0]
        size_t b4i = (size_t)chunk * CHUNK_F4;
        r0 = src4[b4i + tid];        r1 = src4[b4i + tid + 256];
        r2 = src4[b4i + tid + 512];  r3 = src4[b4i + tid + 768];
        r4 = src4[b4i + tid + 1024];
        if (tid < 16) r5 = src4[b4i + tid + 1280];
        float4* w4 = (float4*)buf[0];
        w4[tid] = r0; w4[tid + 256] = r1; w4[tid + 512] = r2;
        w4[tid + 768] = r3; w4[tid + 1024] = r4;
        if (tid < 16) w4[tid + 1280] = r5;
    }
    int cur = 0;
    for (;;) {
        int next = chunk + KC_GRID;
        bool hn = next < KC_CHUNKS;
        __syncthreads();                          // buf[cur] complete (nothing else pending)
        if (hn) {                                 // issue next-chunk loads early
            size_t b4i = (size_t)next * CHUNK_F4;
            r0 = src4[b4i + tid];        r1 = src4[b4i + tid + 256];
            r2 = src4[b4i + tid + 512];  r3 = src4[b4i + tid + 768];
            r4 = src4[b4i + tid + 1024];
            if (tid < 16) r5 = src4[b4i + tid + 1280];
        }
        {   // compute current chunk from LDS (same split/order as verified round-1)
            int r = tid >> 2, q = tid & 3;        // 4 threads per row
            const float* row = buf[cur] + r * 81;
            int kstart = (q == 0) ? 0 : 21 + (q - 1) * 20;   // 21/20/20/20
            float s = 0.0f;
#pragma unroll
            for (int k = 0; k < 20; ++k) s += __expf(row[kstart + k]);
            if (q == 0) s += __expf(row[20]);
            s += __shfl_xor(s, 1);
            s += __shfl_xor(s, 2);
            if (q == 0)
                cls_l[chunk * ROWS_PC + r] = __logf(s) - row[0];
        }
        if (!hn) break;
        {   // drain loads into other buffer (vmcnt hidden under compute above)
            float4* w4 = (float4*)buf[cur ^ 1];
            w4[tid] = r0; w4[tid + 256] = r1; w4[tid + 512] = r2;
            w4[tid + 768] = r3; w4[tid + 1024] = r4;
            if (tid < 16) w4[tid + 1280] = r5;
        }
        chunk = next; cur ^= 1;
    }
}

// ---------------- Kernel B: labels, loc loss, radix keys, positive CE ----------------
// 8 blocks per image, 1092 anchors each. forced[] replaced by a 32-compare
// register check against bestp (last/largest g wins, identical semantics).
__global__ __launch_bounds__(256) void kB(const float* __restrict__ anchors,
    const float* __restrict__ gt_boxes, const int* __restrict__ gt_labels,
    const float* __restrict__ loc_pred, const unsigned char* __restrict__ bestg,
    const unsigned int* __restrict__ bestp, const float* __restrict__ cls_l,
    const float* __restrict__ conf, unsigned int* __restrict__ keyg,
    unsigned char* __restrict__ labg, int* __restrict__ num_pos,
    double* __restrict__ loc_sum, double* __restrict__ cls_pos)
{
    int tid = threadIdx.x;
    int b = blockIdx.x >> 3, seg = blockIdx.x & 7;
    __shared__ float gcx[GG], gcy[GG], gw[GG], gh[GG];
    __shared__ int glab[GG];
    __shared__ unsigned int bp[GG];
    __shared__ double rd[4], rp[4];
    __shared__ int ri[4];
    if (tid < GG) {
        float4 gb = ((const float4*)gt_boxes)[b * GG + tid];
        gcx[tid] = gb.x; gcy[tid] = gb.y; gw[tid] = gb.z; gh[tid] = gb.w;
        glab[tid] = gt_labels[b * GG + tid];
        bp[tid] = bestp[b * GG + tid];
    }
    __syncthreads();

    int aend = (seg + 1) * SEGSZ; if (aend > AA) aend = AA;
    double lsum = 0.0, pc = 0.0; int pcount = 0;
    for (int a = seg * SEGSZ + tid; a < aend; a += 256) {
        int gf = -1;
#pragma unroll
        for (int g = 0; g < GG; ++g)
            if (bp[g] == (unsigned int)a) gf = g;  // ascending: largest g wins
        int gsel;
        if (gf >= 0) gsel = gf;
        else {
            unsigned char bg = bestg[b * AA + a];
            gsel = (bg == 0xFF) ? -1 : (int)bg;
        }
        int lab = 0;
        if (gsel >= 0) {
            lab = glab[gsel];                      // labels in 1..C-1 -> positive
            float4 an = ((const float4*)anchors)[a];
            float e0 = (gcx[gsel] - an.x) / an.z;
            float e1 = (gcy[gsel] - an.y) / an.w;
            float e2 = logf(gw[gsel]) - logf(an.z);
            float e3 = logf(gh[gsel]) - logf(an.w);
            float4 lp = ((const float4*)loc_pred)[b * AA + a];
            float d0 = lp.x - e0, d1 = lp.y - e1, d2 = lp.z - e2, d3 = lp.w - e3;
            float t = 0.0f, ad;
            ad = fabsf(d0); t += (ad < 1.0f) ? 0.5f * d0 * d0 : ad - 0.5f;
            ad = fabsf(d1); t += (ad < 1.0f) ? 0.5f * d1 * d1 : ad - 0.5f;
            ad = fabsf(d2); t += (ad < 1.0f) ? 0.5f * d2 * d2 : ad - 0.5f;
            ad = fabsf(d3); t += (ad < 1.0f) ? 0.5f * d3 * d3 : ad - 0.5f;
            lsum += (double)t;
            pcount++;
        }
        labg[b * AA + a] = (unsigned char)lab;
        float sv = cls_l[b * AA + a];
        unsigned int key;
        if (lab > 0) {
            size_t rowb = ((size_t)(b * AA + a)) * 81;
            pc += (double)(sv + conf[rowb] - conf[rowb + lab]);  // lse - conf[label]
            key = 0u;                              // positives excluded from mining
        } else {
            key = __float_as_uint(fmaxf(sv, 0.0f)); // guard tiny negative rounding
        }
        keyg[b * AA + a] = key;
    }
#pragma unroll
    for (int off = 32; off > 0; off >>= 1) {
        lsum += __shfl_down(lsum, off);
        pc += __shfl_down(pc, off);
        pcount += __shfl_down(pcount, off);
    }
    if ((tid & 63) == 0) { rd[tid >> 6] = lsum; rp[tid >> 6] = pc; ri[tid >> 6] = pcount; }
    __syncthreads();
    if (tid == 0) {
        double L = rd[0] + rd[1] + rd[2] + rd[3];
        double C = rp[0] + rp[1] + rp[2] + rp[3];
        int P = ri[0] + ri[1] + ri[2] + ri[3];
        if (P) atomicAdd(&num_pos[b], P);
        atomicAdd(&loc_sum[b], L);
        atomicAdd(&cls_pos[b], C);
    }
}

// ---------------- Kernel E: radix-select top-k + final reduce ----------------
__global__ __launch_bounds__(1024, 4) void kE(const unsigned int* __restrict__ keyg,
    const unsigned char* __restrict__ labg, const int* __restrict__ num_pos,
    const double* __restrict__ loc_sum, const double* __restrict__ cls_pos,
    unsigned int* __restrict__ ticket, double* __restrict__ btot_acc,
    int* __restrict__ np_acc, float* __restrict__ out)
{
    int b = blockIdx.x, tid = threadIdx.x;
    __shared__ unsigned int cl[AA];               // 34928 B
    __shared__ unsigned int whist[16 * 256];      // per-wave histograms
    __shared__ unsigned int hist[256];
    __shared__ double red_d[16];
    __shared__ unsigned int red_u[16];
    __shared__ unsigned int sh_prefix, sh_remaining;

    for (int i = tid; i < AA; i += 1024) cl[i] = keyg[b * AA + i];
    int np_ = num_pos[b];
    int k = min(3 * np_, AA - 1);                 // num_neg = min(3*num_pos, A-1)
    if (tid == 0) { sh_prefix = 0u; sh_remaining = (unsigned int)k; }
    __syncthreads();

    double topk = 0.0;
    int p_t_pos = 0;                              // positives inside neg_mask (tie at 0)
    if (k > 0) {
        for (int shift = 24; shift >= 0; shift -= 8) {
            for (int j = tid; j < 4096; j += 1024) whist[j] = 0u;
            __syncthreads();
            unsigned int mask = (shift == 24) ? 0u : (0xFFFFFFFFu << (shift + 8));
            unsigned int pre = sh_prefix;
            unsigned int* myh = whist + (tid >> 6) * 256;
            for (int i = tid; i < AA; i += 1024) {
                unsigned int u = cl[i];
                if ((u & mask) == pre) atomicAdd(&myh[(u >> shift) & 255], 1u);
            }
            __syncthreads();
            if (tid < 256) {
                unsigned int t = 0;
#pragma unroll
                for (int w = 0; w < 16; ++w) t += whist[w * 256 + tid];
                hist[tid] = t;
            }
            __syncthreads();
            if (tid < 64) {                       // wave-parallel digit select
                int l = tid;
                unsigned int h4 = hist[4 * l] + hist[4 * l + 1]
                                + hist[4 * l + 2] + hist[4 * l + 3];
                unsigned int S = h4;              // suffix sum over lane groups
#pragma unroll
                for (int off = 1; off < 64; off <<= 1) {
                    unsigned int o = __shfl_down(S, off);
                    S += (l + off < 64) ? o : 0u;
                }
                unsigned int rem = sh_remaining;
                unsigned long long ball = __ballot(S >= rem);  // lanes 0..L set
                int L = 63 - __clzll(ball);
                if (l == L) {
                    unsigned int rem2 = rem - (S - h4);
                    unsigned int c = 0;
                    for (int dd = 4 * L + 3; dd >= 4 * L; --dd) {
                        c += hist[dd];
                        if (c >= rem2) {
                            sh_prefix = pre | ((unsigned int)dd << shift);
                            sh_remaining = rem2 - (c - hist[dd]);
                            break;
                        }
                    }
                }
            }
            __syncthreads();
        }
        unsigned int vbits = sh_prefix;
        unsigned int myc = 0; double mys = 0.0;
        for (int i = tid; i < AA; i += 1024) {
            unsigned int u = cl[i];
            if (u > vbits) { myc++; mys += (double)__uint_as_float(u); }
        }
#pragma unroll
        for (int off = 32; off > 0; off >>= 1) {
            myc += __shfl_down(myc, off);
            mys += __shfl_down(mys, off);
        }
        if ((tid & 63) == 0) { red_u[tid >> 6] = myc; red_d[tid >> 6] = mys; }
        __syncthreads();
        if (tid == 0) {
            unsigned int cnt_gt = 0; double sum_gt = 0.0;
            for (int w = 0; w < 16; ++w) { cnt_gt += red_u[w]; sum_gt += red_d[w]; }
            topk = sum_gt + (double)(k - (int)cnt_gt) * (double)__uint_as_float(vbits);
            if (vbits == 0u) {                    // rare tie-at-zero path
                int t = k - (int)cnt_gt, c2 = 0;
                for (int i = 0; i < AA && c2 < t; ++i) {
                    if (cl[i] == 0u) { c2++; if (labg[b * AA + i] > 0) p_t_pos++; }
                }
            }
        }
    }
    if (tid == 0) {
        int unsampled = AA - np_ - k + p_t_pos;
        double clsb = cls_pos[b] + topk + (double)unsampled * (double)logf(81.0f);
        double myb = loc_sum[b] + clsb;
        atomicAdd(btot_acc, myb);                 // device-scope by default
        atomicAdd(np_acc, np_);
        __threadfence();
        unsigned int t = atomicAdd(ticket, 1u);
        if (t == BB - 1) {                        // last block: all adds happened-before
            double tt = atomicAdd(btot_acc, 0.0); // returns old = full sum
            int nn = atomicAdd(np_acc, 0);
            out[0] = (float)(tt / (double)nn);
        }
    }
}

extern "C" void kernel_launch(void* const* d_in, const int* in_sizes, int n_in,
                              void* d_out, int out_size, void* d_ws, size_t ws_size,
                              hipStream_t stream) {
    (void)in_sizes; (void)n_in; (void)out_size; (void)ws_size;
    const float* loc_pred  = (const float*)d_in[0];
    const float* conf_pred = (const float*)d_in[1];
    const float* anchors   = (const float*)d_in[2];
    const float* gt_boxes  = (const float*)d_in[3];
    const int*   gt_labels = (const int*)d_in[4];

    char* ws = (char*)d_ws;
    unsigned int*  bestp    = (unsigned int*)(ws + 0);
    unsigned char* bestg    = (unsigned char*)(ws + 8192);
    float*         cls_l    = (float*)(ws + 567040);
    unsigned int*  keyg     = (unsigned int*)(ws + 2802432);
    unsigned char* labg     = (unsigned char*)(ws + 5037824);
    int*           num_pos  = (int*)(ws + 5596672);
    double*        loc_sum  = (double*)(ws + 5596928);
    double*        cls_pos  = (double*)(ws + 5597440);
    unsigned int*  ticket   = (unsigned int*)(ws + 5597952);
    double*        btot_acc = (double*)(ws + 5597960);
    int*           np_acc   = (int*)(ws + 5597968);

    kA<<<KA_BLOCKS, 256, 0, stream>>>(anchors, gt_boxes, bestg, bestp,
        num_pos, loc_sum, cls_pos, ticket, btot_acc, np_acc);
    kC<<<KC_GRID, 256, 0, stream>>>(conf_pred, cls_l);
    kB<<<KB_BLOCKS, 256, 0, stream>>>(anchors, gt_boxes, gt_labels, loc_pred,
        bestg, bestp, cls_l, conf_pred, keyg, labg, num_pos, loc_sum, cls_pos);
    kE<<<BB, 1024, 0, stream>>>(keyg, labg, num_pos, loc_sum, cls_pos,
        ticket, btot_acc, np_acc, (float*)d_out);
}

// Round 3
// 315.973 us; speedup vs baseline: 1.1749x; 1.0227x over previous
//
#include <hip/hip_runtime.h>
#include <math.h>

// Keep box arithmetic bit-identical to numpy fp32 (no fma contraction):
// matching decisions (iou > 0.5, argmax) must not flip.
#pragma clang fp contract(off)

#define BB 64
#define AA 8732
#define CC 81
#define GG 32
#define A_BLOCKS 35                 // ceil(8732/256)
#define KC_GRID 768                 // C role: 3 blocks/CU at 41.5 KB LDS
#define KA1_BLOCKS (BB*A_BLOCKS)    // 2240
#define KA2_BLOCKS (BB*GG/4)        // 512
#define TOT_BLOCKS (KC_GRID+KA1_BLOCKS+KA2_BLOCKS)
#define ROWS_PC 64                  // conf rows per kC chunk
#define KC_CHUNKS (BB*AA/ROWS_PC)   // 8732 chunks, exact
#define CHUNK_F4 (ROWS_PC*81/4)     // 1296 float4 per chunk, exact

// ---- workspace layout (bytes) ----
// [0,8192)           bestp  u32[B*G]
// [8192,567040)      bestg  u8[B*A]
// [567040,2802432)   cls_l  f32[B*A]
// [2802432,2802436)  ticket u32      (zeroed by kAC block 0)
// [2802440,2802448)  btot   f64
// [2802448,2802452)  np_acc i32

__device__ __forceinline__ void iou_upd(const float4 an, int a,
    float gx1, float gy1, float gx2, float gy2, float gar2,
    float& bi, float& bu, int& ba)
{
    float ax1 = an.x - an.z / 2.0f, ay1 = an.y - an.w / 2.0f;
    float ax2 = an.x + an.z / 2.0f, ay2 = an.y + an.w / 2.0f;
    float aar = (ax2 - ax1) * (ay2 - ay1);
    float ltx = fmaxf(gx1, ax1), lty = fmaxf(gy1, ay1);
    float rbx = fminf(gx2, ax2), rby = fminf(gy2, ay2);
    float w = fmaxf(rbx - ltx, 0.0f), h = fmaxf(rby - lty, 0.0f);
    float inter = w * h;
    float uni = gar2 + aar - inter;
    if (inter * bu > bi * uni) { bi = inter; bu = uni; ba = a; }  // strict >: first max
}

// ---------------- Kernel AC: one dispatch, three roles ----------------
// blocks [0,768):      C  — conf logsumexp, 1-iteration-deep reg prefetch + LDS dbuf
// blocks [768,3008):   A1 — per-anchor best gt (thread per anchor)
// blocks [3008,3520):  A2 — per-gt best anchor (wave per (b,g)), 4x-batched loads
// iou compare by cross-multiplication: iou1>iou2 <=> i1*u2 > i2*u1 (all >0);
// threshold iou>0.5 <=> 2*i > u. No division anywhere.
__global__ __launch_bounds__(256) void kAC(const float* __restrict__ anchors,
    const float* __restrict__ gt_boxes, const float* __restrict__ conf,
    unsigned char* __restrict__ bestg, unsigned int* __restrict__ bestp,
    float* __restrict__ cls_l, unsigned int* __restrict__ ticket,
    double* __restrict__ btot_acc, int* __restrict__ np_acc)
{
    __shared__ float buf[2][ROWS_PC * 81];        // 41.5 KB (all roles allocate it)
    int tid = threadIdx.x;
    if (blockIdx.x == 0 && tid == 0) {            // init for kBE's final reduce
        *ticket = 0u; *btot_acc = 0.0; *np_acc = 0;
    }
    if (blockIdx.x < KC_GRID) {
        // ---- role C ----
        const float4* __restrict__ src4 = (const float4*)conf;
        float4 r0, r1, r2, r3, r4, r5;
        int c0 = blockIdx.x;
        {   // prologue: stage chunk c0 -> buf[0], then prefetch c0+GRID into regs
            size_t b4 = (size_t)c0 * CHUNK_F4;
            r0 = src4[b4 + tid];        r1 = src4[b4 + tid + 256];
            r2 = src4[b4 + tid + 512];  r3 = src4[b4 + tid + 768];
            r4 = src4[b4 + tid + 1024];
            if (tid < 16) r5 = src4[b4 + tid + 1280];
            float4* w4 = (float4*)buf[0];
            w4[tid] = r0; w4[tid + 256] = r1; w4[tid + 512] = r2;
            w4[tid + 768] = r3; w4[tid + 1024] = r4;
            if (tid < 16) w4[tid + 1280] = r5;
            if (c0 + KC_GRID < KC_CHUNKS) {
                b4 = (size_t)(c0 + KC_GRID) * CHUNK_F4;
                r0 = src4[b4 + tid];        r1 = src4[b4 + tid + 256];
                r2 = src4[b4 + tid + 512];  r3 = src4[b4 + tid + 768];
                r4 = src4[b4 + tid + 1024];
                if (tid < 16) r5 = src4[b4 + tid + 1280];
            }
        }
        int cur = 0;
        for (int c = c0; c < KC_CHUNKS; c += KC_GRID) {
            bool hn = (c + KC_GRID) < KC_CHUNKS;  // regs hold chunk c+GRID iff hn
            __syncthreads();                      // prev compute done; buf[cur^1] free
            if (hn) {                             // drain prefetch (issued 1 iter ago)
                float4* w4 = (float4*)buf[cur ^ 1];
                w4[tid] = r0; w4[tid + 256] = r1; w4[tid + 512] = r2;
                w4[tid + 768] = r3; w4[tid + 1024] = r4;
                if (tid < 16) w4[tid + 1280] = r5;
            }
            if (c + 2 * KC_GRID < KC_CHUNKS) {    // issue next prefetch immediately
                size_t b4 = (size_t)(c + 2 * KC_GRID) * CHUNK_F4;
                r0 = src4[b4 + tid];        r1 = src4[b4 + tid + 256];
                r2 = src4[b4 + tid + 512];  r3 = src4[b4 + tid + 768];
                r4 = src4[b4 + tid + 1024];
                if (tid < 16) r5 = src4[b4 + tid + 1280];
            }
            {   // compute chunk c from buf[cur] (verified 21/20/20/20 split)
                int r = tid >> 2, q = tid & 3;    // 4 threads per row
                const float* row = buf[cur] + r * 81;
                int kstart = (q == 0) ? 0 : 21 + (q - 1) * 20;
                float s = 0.0f;
#pragma unroll
                for (int k = 0; k < 20; ++k) s += __expf(row[kstart + k]);
                if (q == 0) s += __expf(row[20]);
                s += __shfl_xor(s, 1);
                s += __shfl_xor(s, 2);
                if (q == 0)
                    cls_l[c * ROWS_PC + r] = __logf(s) - row[0];  // idx01=0 for negatives
            }
            cur ^= 1;
        }
    } else if (blockIdx.x < KC_GRID + KA1_BLOCKS) {
        // ---- role A1 ---- (gt tiles overlay the C-role LDS buffer)
        float4* gco = (float4*)buf;               // 32 float4
        float* gar = ((float*)buf) + 128;         // 32 floats
        int blk = blockIdx.x - KC_GRID;
        int b = blk / A_BLOCKS, ca = blk % A_BLOCKS;
        int a = ca * 256 + tid;
        if (tid < GG) {
            float4 gb = ((const float4*)gt_boxes)[b * GG + tid];
            float x1 = gb.x - gb.z / 2.0f, y1 = gb.y - gb.w / 2.0f;
            float x2 = gb.x + gb.z / 2.0f, y2 = gb.y + gb.w / 2.0f;
            gco[tid] = make_float4(x1, y1, x2, y2);
            gar[tid] = (x2 - x1) * (y2 - y1);     // same rounding as reference
        }
        __syncthreads();
        if (a >= AA) return;
        float4 an = ((const float4*)anchors)[a];
        float ax1 = an.x - an.z / 2.0f, ay1 = an.y - an.w / 2.0f;
        float ax2 = an.x + an.z / 2.0f, ay2 = an.y + an.w / 2.0f;
        float aar = (ax2 - ax1) * (ay2 - ay1);
        float bi = -1.0f, bu = 1.0f; int bgi = 0; // first compare takes g=0
#pragma unroll
        for (int g = 0; g < GG; ++g) {
            float4 cbox = gco[g];
            float ltx = fmaxf(cbox.x, ax1), lty = fmaxf(cbox.y, ay1);
            float rbx = fminf(cbox.z, ax2), rby = fminf(cbox.w, ay2);
            float w = fmaxf(rbx - ltx, 0.0f), h = fmaxf(rby - lty, 0.0f);
            float inter = w * h;
            float uni = gar[g] + aar - inter;
            if (inter * bu > bi * uni) { bi = inter; bu = uni; bgi = g; }
        }
        bestg[b * AA + a] = (2.0f * bi > bu) ? (unsigned char)bgi : (unsigned char)0xFF;
    } else {
        // ---- role A2 ----
        int wv = tid >> 6, lane = tid & 63;
        int pair = (blockIdx.x - KC_GRID - KA1_BLOCKS) * 4 + wv;   // 0..2047
        int b = pair >> 5, g = pair & 31;
        float4 gb = ((const float4*)gt_boxes)[b * GG + g];
        float gx1 = gb.x - gb.z / 2.0f, gy1 = gb.y - gb.w / 2.0f;
        float gx2 = gb.x + gb.z / 2.0f, gy2 = gb.y + gb.w / 2.0f;
        float gar2 = (gx2 - gx1) * (gy2 - gy1);
        const float4* __restrict__ A4 = (const float4*)anchors;
        float bi = -1.0f, bu = 1.0f; int ba = 0;
        // 8732 = 64*136 + 28; a = lane + 64k ascending (preserves tie order)
        for (int k0 = 0; k0 < 136; k0 += 4) {
            int a0 = lane + 64 * k0;
            float4 v0 = A4[a0];                   // 4 independent loads in flight
            float4 v1 = A4[a0 + 64];
            float4 v2 = A4[a0 + 128];
            float4 v3 = A4[a0 + 192];
            iou_upd(v0, a0,       gx1, gy1, gx2, gy2, gar2, bi, bu, ba);
            iou_upd(v1, a0 + 64,  gx1, gy1, gx2, gy2, gar2, bi, bu, ba);
            iou_upd(v2, a0 + 128, gx1, gy1, gx2, gy2, gar2, bi, bu, ba);
            iou_upd(v3, a0 + 192, gx1, gy1, gx2, gy2, gar2, bi, bu, ba);
        }
        if (lane < 28) {                          // tail: a = 8704..8731
            int a = 8704 + lane;
            iou_upd(A4[a], a, gx1, gy1, gx2, gy2, gar2, bi, bu, ba);
        }
        // wave butterfly-reduce, lexicographic (iou desc, a asc)
#pragma unroll
        for (int off = 32; off > 0; off >>= 1) {
            float oi = __shfl_down(bi, off);
            float ou = __shfl_down(bu, off);
            int   oa = __shfl_down(ba, off);
            float p1 = oi * bu, p2 = bi * ou;
            bool take = (p1 > p2) || ((p1 == p2) && (oa < ba));
            if (take) { bi = oi; bu = ou; ba = oa; }
        }
        if (lane == 0) bestp[pair] = (unsigned int)ba;
    }
}

// ---------------- Kernel BE: finalize + radix top-k + final reduce, fused ----------------
// One block per image, 1024 threads. Keys/labels live only in LDS (no global
// round trip). Radix pass-1 histogram uses leader-ballot aggregation: nearly
// all keys share 1-2 exponent-byte digits, so one ballot+popcount+atomic per
// digit replaces ~8.7k serialized same-bank LDS atomics. Spread digits
// (passes 2-4) fall back to per-lane atomics across 256 bins (few conflicts).
__global__ __launch_bounds__(1024, 4) void kBE(const float* __restrict__ anchors,
    const float* __restrict__ gt_boxes, const int* __restrict__ gt_labels,
    const float* __restrict__ loc_pred, const unsigned char* __restrict__ bestg,
    const unsigned int* __restrict__ bestp, const float* __restrict__ cls_l,
    const float* __restrict__ conf, unsigned int* __restrict__ ticket,
    double* __restrict__ btot_acc, int* __restrict__ np_acc,
    float* __restrict__ out)
{
    int b = blockIdx.x, tid = threadIdx.x, lane = tid & 63;
    __shared__ unsigned int cl[AA];               // 34928 B
    __shared__ unsigned char slab[AA];            // 8732 B
    __shared__ unsigned int hist[256];
    __shared__ float gcx[GG], gcy[GG], gw[GG], gh[GG];
    __shared__ int glab[GG];
    __shared__ unsigned int bp[GG];
    __shared__ double red_d[16], red_p[16];
    __shared__ int red_i[16];
    __shared__ unsigned int red_u[16];
    __shared__ unsigned int sh_prefix, sh_remaining;
    __shared__ int sh_np;
    __shared__ double sh_loc, sh_pc;

    if (tid < GG) {
        float4 gb = ((const float4*)gt_boxes)[b * GG + tid];
        gcx[tid] = gb.x; gcy[tid] = gb.y; gw[tid] = gb.z; gh[tid] = gb.w;
        glab[tid] = gt_labels[b * GG + tid];
        bp[tid] = bestp[b * GG + tid];
    }
    __syncthreads();

    // ---- phase B: labels, loc loss, keys, positive CE ----
    double lsum = 0.0, pc = 0.0; int pcount = 0;
    for (int a = tid; a < AA; a += 1024) {
        int gf = -1;
#pragma unroll
        for (int g = 0; g < GG; ++g)
            if (bp[g] == (unsigned int)a) gf = g; // ascending: largest g wins
        int gsel;
        if (gf >= 0) gsel = gf;
        else {
            unsigned char bg = bestg[b * AA + a];
            gsel = (bg == 0xFF) ? -1 : (int)bg;
        }
        int lab = 0;
        if (gsel >= 0) {
            lab = glab[gsel];                     // labels in 1..C-1 -> positive
            float4 an = ((const float4*)anchors)[a];
            float e0 = (gcx[gsel] - an.x) / an.z;
            float e1 = (gcy[gsel] - an.y) / an.w;
            float e2 = logf(gw[gsel]) - logf(an.z);
            float e3 = logf(gh[gsel]) - logf(an.w);
            float4 lp = ((const float4*)loc_pred)[b * AA + a];
            float d0 = lp.x - e0, d1 = lp.y - e1, d2 = lp.z - e2, d3 = lp.w - e3;
            float t = 0.0f, ad;
            ad = fabsf(d0); t += (ad < 1.0f) ? 0.5f * d0 * d0 : ad - 0.5f;
            ad = fabsf(d1); t += (ad < 1.0f) ? 0.5f * d1 * d1 : ad - 0.5f;
            ad = fabsf(d2); t += (ad < 1.0f) ? 0.5f * d2 * d2 : ad - 0.5f;
            ad = fabsf(d3); t += (ad < 1.0f) ? 0.5f * d3 * d3 : ad - 0.5f;
            lsum += (double)t;
            pcount++;
        }
        slab[a] = (unsigned char)lab;
        float sv = cls_l[b * AA + a];
        if (lab > 0) {
            size_t rowb = ((size_t)(b * AA + a)) * 81;
            pc += (double)(sv + conf[rowb] - conf[rowb + lab]);  // lse - conf[label]
            cl[a] = 0u;                           // positives excluded from mining
        } else {
            cl[a] = __float_as_uint(fmaxf(sv, 0.0f));  // guard tiny negative rounding
        }
    }
#pragma unroll
    for (int off = 32; off > 0; off >>= 1) {
        lsum += __shfl_down(lsum, off);
        pc += __shfl_down(pc, off);
        pcount += __shfl_down(pcount, off);
    }
    if (lane == 0) { red_d[tid >> 6] = lsum; red_p[tid >> 6] = pc; red_i[tid >> 6] = pcount; }
    __syncthreads();
    if (tid == 0) {
        double L = 0.0, C = 0.0; int P = 0;
        for (int w = 0; w < 16; ++w) { L += red_d[w]; C += red_p[w]; P += red_i[w]; }
        sh_loc = L; sh_pc = C; sh_np = P;
        sh_prefix = 0u;
        sh_remaining = (unsigned int)min(3 * P, AA - 1);
    }
    __syncthreads();
    int np_ = sh_np;
    int k = min(3 * np_, AA - 1);                 // num_neg = min(3*num_pos, A-1)

    // ---- phase E: radix-select top-k ----
    double topk = 0.0;
    int p_t_pos = 0;                              // positives inside neg_mask (tie at 0)
    if (k > 0) {
        for (int shift = 24; shift >= 0; shift -= 8) {
            if (tid < 256) hist[tid] = 0u;
            __syncthreads();
            unsigned int mask = (shift == 24) ? 0u : (0xFFFFFFFFu << (shift + 8));
            unsigned int pre = sh_prefix;
#pragma unroll
            for (int it = 0; it < 9; ++it) {      // 9*1024 >= 8732; wave-uniform trips
                int i = tid + it * 1024;
                bool in = (i < AA);
                unsigned int u = in ? cl[i] : 0u;
                bool act = in && ((u & mask) == pre);
                unsigned int d = (u >> shift) & 255u;
                unsigned long long actm = __ballot(act);
                while (actm) {                    // aggregate dominant digits
                    int src = __builtin_ctzll(actm);
                    unsigned int d0 = (unsigned int)__shfl((int)d, src);
                    unsigned long long m = __ballot(act && (d == d0));
                    int c = __popcll(m);
                    if (c < 8) break;             // spread digits -> per-lane fallback
                    if (lane == src) atomicAdd(&hist[d0], (unsigned int)c);
                    actm &= ~m;
                }
                if ((actm >> lane) & 1ull) atomicAdd(&hist[d], 1u);
            }
            __syncthreads();
            if (tid < 64) {                       // wave-parallel digit select
                int l = tid;
                unsigned int h4 = hist[4 * l] + hist[4 * l + 1]
                                + hist[4 * l + 2] + hist[4 * l + 3];
                unsigned int S = h4;              // suffix sum over lane groups
#pragma unroll
                for (int off = 1; off < 64; off <<= 1) {
                    unsigned int o = __shfl_down(S, off);
                    S += (l + off < 64) ? o : 0u;
                }
                unsigned int rem = sh_remaining;
                unsigned long long ball = __ballot(S >= rem);  // lanes 0..L set
                int L = 63 - __clzll(ball);
                if (l == L) {
                    unsigned int rem2 = rem - (S - h4);
                    unsigned int c = 0;
                    for (int dd = 4 * L + 3; dd >= 4 * L; --dd) {
                        c += hist[dd];
                        if (c >= rem2) {
                            sh_prefix = pre | ((unsigned int)dd << shift);
                            sh_remaining = rem2 - (c - hist[dd]);
                            break;
                        }
                    }
                }
            }
            __syncthreads();
        }
        unsigned int vbits = sh_prefix;
        unsigned int myc = 0; double mys = 0.0;
        for (int i = tid; i < AA; i += 1024) {
            unsigned int u = cl[i];
            if (u > vbits) { myc++; mys += (double)__uint_as_float(u); }
        }
#pragma unroll
        for (int off = 32; off > 0; off >>= 1) {
            myc += __shfl_down(myc, off);
            mys += __shfl_down(mys, off);
        }
        if (lane == 0) { red_u[tid >> 6] = myc; red_d[tid >> 6] = mys; }
        __syncthreads();
        if (tid == 0) {
            unsigned int cnt_gt = 0; double sum_gt = 0.0;
            for (int w = 0; w < 16; ++w) { cnt_gt += red_u[w]; sum_gt += red_d[w]; }
            topk = sum_gt + (double)(k - (int)cnt_gt) * (double)__uint_as_float(vbits);
            if (vbits == 0u) {                    // rare tie-at-zero path
                int t = k - (int)cnt_gt, c2 = 0;
                for (int i = 0; i < AA && c2 < t; ++i) {
                    if (cl[i] == 0u) { c2++; if (slab[i] > 0) p_t_pos++; }
                }
            }
        }
    }
    if (tid == 0) {
        int unsampled = AA - np_ - k + p_t_pos;
        double clsb = sh_pc + topk + (double)unsampled * (double)logf(81.0f);
        double myb = sh_loc + clsb;
        atomicAdd(btot_acc, myb);                 // device-scope by default
        atomicAdd(np_acc, np_);
        __threadfence();
        unsigned int t = atomicAdd(ticket, 1u);
        if (t == BB - 1) {                        // last block: all adds happened-before
            double tt = atomicAdd(btot_acc, 0.0); // returns old = full sum
            int nn = atomicAdd(np_acc, 0);
            out[0] = (float)(tt / (double)nn);
        }
    }
}

extern "C" void kernel_launch(void* const* d_in, const int* in_sizes, int n_in,
                              void* d_out, int out_size, void* d_ws, size_t ws_size,
                              hipStream_t stream) {
    (void)in_sizes; (void)n_in; (void)out_size; (void)ws_size;
    const float* loc_pred  = (const float*)d_in[0];
    const float* conf_pred = (const float*)d_in[1];
    const float* anchors   = (const float*)d_in[2];
    const float* gt_boxes  = (const float*)d_in[3];
    const int*   gt_labels = (const int*)d_in[4];

    char* ws = (char*)d_ws;
    unsigned int*  bestp    = (unsigned int*)(ws + 0);
    unsigned char* bestg    = (unsigned char*)(ws + 8192);
    float*         cls_l    = (float*)(ws + 567040);
    unsigned int*  ticket   = (unsigned int*)(ws + 2802432);
    double*        btot_acc = (double*)(ws + 2802440);
    int*           np_acc   = (int*)(ws + 2802448);

    kAC<<<TOT_BLOCKS, 256, 0, stream>>>(anchors, gt_boxes, conf_pred,
        bestg, bestp, cls_l, ticket, btot_acc, np_acc);
    kBE<<<BB, 1024, 0, stream>>>(anchors, gt_boxes, gt_labels, loc_pred,
        bestg, bestp, cls_l, conf_pred, ticket, btot_acc, np_acc, (float*)d_out);
}

// Round 4
// 313.983 us; speedup vs baseline: 1.1823x; 1.0063x over previous
//
#include <hip/hip_runtime.h>
#include <math.h>

// Keep box arithmetic bit-identical to numpy fp32 (no fma contraction):
// matching decisions (iou > 0.5, argmax) must not flip.
#pragma clang fp contract(off)

#define BB 64
#define AA 8732
#define CC 81
#define GG 32
#define A_BLOCKS 35                 // ceil(8732/256)
#define KC_GRID 1536                // C role: 6 blocks/CU at 20.7 KB LDS
#define KA1_BLOCKS (BB*A_BLOCKS)    // 2240
#define KA2_BLOCKS (BB*GG/4)        // 512
#define TOT_BLOCKS (KC_GRID+KA1_BLOCKS+KA2_BLOCKS)
#define ROWS_PC 64                  // conf rows per kC chunk
#define KC_CHUNKS (BB*AA/ROWS_PC)   // 8732 chunks, exact
#define CHUNK_F4 (ROWS_PC*81/4)     // 1296 float4 per chunk, exact

// ---- workspace layout (bytes) ----
// [0,8192)           bestp  u32[B*G]
// [8192,567040)      bestg  u8[B*A]
// [567040,2802432)   cls_l  f32[B*A]
// [2802432,2802436)  ticket u32      (zeroed by kAC block 0)
// [2802440,2802448)  btot   f64
// [2802448,2802452)  np_acc i32

__device__ __forceinline__ void iou_upd(const float4 an, int a,
    float gx1, float gy1, float gx2, float gy2, float gar2,
    float& bi, float& bu, int& ba)
{
    float ax1 = an.x - an.z / 2.0f, ay1 = an.y - an.w / 2.0f;
    float ax2 = an.x + an.z / 2.0f, ay2 = an.y + an.w / 2.0f;
    float aar = (ax2 - ax1) * (ay2 - ay1);
    float ltx = fmaxf(gx1, ax1), lty = fmaxf(gy1, ay1);
    float rbx = fminf(gx2, ax2), rby = fminf(gy2, ay2);
    float w = fmaxf(rbx - ltx, 0.0f), h = fmaxf(rby - lty, 0.0f);
    float inter = w * h;
    float uni = gar2 + aar - inter;
    if (inter * bu > bi * uni) { bi = inter; bu = uni; ba = a; }  // strict >: first max
}

// ---------------- Kernel AC: one dispatch, three roles ----------------
// blocks [0,1536):     C  — conf logsumexp, SINGLE 20.7 KB buffer (7 blocks/CU)
//                      with 1-iteration reg prefetch; 2 barriers/iter; load
//                      latency hides under compute + 24 resident waves/CU.
// blocks [1536,3776):  A1 — per-anchor best gt (thread per anchor)
// blocks [3776,4288):  A2 — per-gt best anchor (wave per (b,g)), 8x-batched
// iou compare by cross-multiplication: iou1>iou2 <=> i1*u2 > i2*u1 (all >0);
// threshold iou>0.5 <=> 2*i > u. No division anywhere.
__global__ __launch_bounds__(256) void kAC(const float* __restrict__ anchors,
    const float* __restrict__ gt_boxes, const float* __restrict__ conf,
    unsigned char* __restrict__ bestg, unsigned int* __restrict__ bestp,
    float* __restrict__ cls_l, unsigned int* __restrict__ ticket,
    double* __restrict__ btot_acc, int* __restrict__ np_acc)
{
    __shared__ float buf[ROWS_PC * 81];           // 20736 B (7 blocks/CU)
    int tid = threadIdx.x;
    if (blockIdx.x == 0 && tid == 0) {            // init for kBE's final reduce
        *ticket = 0u; *btot_acc = 0.0; *np_acc = 0;
    }
    if (blockIdx.x < KC_GRID) {
        // ---- role C ----
        const float4* __restrict__ src4 = (const float4*)conf;
        float4* buf4 = (float4*)buf;
        float4 r0, r1, r2, r3, r4, r5;
        int c0 = blockIdx.x;
        {   // prologue: load chunk c0 -> regs -> buf
            size_t b4 = (size_t)c0 * CHUNK_F4;
            r0 = src4[b4 + tid];        r1 = src4[b4 + tid + 256];
            r2 = src4[b4 + tid + 512];  r3 = src4[b4 + tid + 768];
            r4 = src4[b4 + tid + 1024];
            if (tid < 16) r5 = src4[b4 + tid + 1280];
            buf4[tid] = r0; buf4[tid + 256] = r1; buf4[tid + 512] = r2;
            buf4[tid + 768] = r3; buf4[tid + 1024] = r4;
            if (tid < 16) buf4[tid + 1280] = r5;
        }
        for (int c = c0; c < KC_CHUNKS; c += KC_GRID) {
            int nx = c + KC_GRID;
            __syncthreads();                      // buf writes visible to all
            if (nx < KC_CHUNKS) {                 // issue next-chunk loads NOW;
                size_t b4 = (size_t)nx * CHUNK_F4;//  latency hides under compute
                r0 = src4[b4 + tid];        r1 = src4[b4 + tid + 256];
                r2 = src4[b4 + tid + 512];  r3 = src4[b4 + tid + 768];
                r4 = src4[b4 + tid + 1024];
                if (tid < 16) r5 = src4[b4 + tid + 1280];
            }
            {   // compute chunk c from buf (verified 21/20/20/20 split)
                int r = tid >> 2, q = tid & 3;    // 4 threads per row
                const float* row = buf + r * 81;
                int kstart = (q == 0) ? 0 : 21 + (q - 1) * 20;
                float s = 0.0f;
#pragma unroll
                for (int k = 0; k < 20; ++k) s += __expf(row[kstart + k]);
                if (q == 0) s += __expf(row[20]);
                s += __shfl_xor(s, 1);
                s += __shfl_xor(s, 2);
                if (q == 0)
                    cls_l[c * ROWS_PC + r] = __logf(s) - row[0];  // idx01=0 for negatives
            }
            if (nx < KC_CHUNKS) {
                __syncthreads();                  // compute reads done; buf reusable
                buf4[tid] = r0; buf4[tid + 256] = r1; buf4[tid + 512] = r2;
                buf4[tid + 768] = r3; buf4[tid + 1024] = r4;
                if (tid < 16) buf4[tid + 1280] = r5;
            }
        }
    } else if (blockIdx.x < KC_GRID + KA1_BLOCKS) {
        // ---- role A1 ---- (gt tiles overlay the C-role LDS buffer)
        float4* gco = (float4*)buf;               // 32 float4
        float* gar = buf + 128;                   // 32 floats
        int blk = blockIdx.x - KC_GRID;
        int b = blk / A_BLOCKS, ca = blk % A_BLOCKS;
        int a = ca * 256 + tid;
        if (tid < GG) {
            float4 gb = ((const float4*)gt_boxes)[b * GG + tid];
            float x1 = gb.x - gb.z / 2.0f, y1 = gb.y - gb.w / 2.0f;
            float x2 = gb.x + gb.z / 2.0f, y2 = gb.y + gb.w / 2.0f;
            gco[tid] = make_float4(x1, y1, x2, y2);
            gar[tid] = (x2 - x1) * (y2 - y1);     // same rounding as reference
        }
        __syncthreads();
        if (a >= AA) return;
        float4 an = ((const float4*)anchors)[a];
        float ax1 = an.x - an.z / 2.0f, ay1 = an.y - an.w / 2.0f;
        float ax2 = an.x + an.z / 2.0f, ay2 = an.y + an.w / 2.0f;
        float aar = (ax2 - ax1) * (ay2 - ay1);
        float bi = -1.0f, bu = 1.0f; int bgi = 0; // first compare takes g=0
#pragma unroll
        for (int g = 0; g < GG; ++g) {
            float4 cbox = gco[g];
            float ltx = fmaxf(cbox.x, ax1), lty = fmaxf(cbox.y, ay1);
            float rbx = fminf(cbox.z, ax2), rby = fminf(cbox.w, ay2);
            float w = fmaxf(rbx - ltx, 0.0f), h = fmaxf(rby - lty, 0.0f);
            float inter = w * h;
            float uni = gar[g] + aar - inter;
            if (inter * bu > bi * uni) { bi = inter; bu = uni; bgi = g; }
        }
        bestg[b * AA + a] = (2.0f * bi > bu) ? (unsigned char)bgi : (unsigned char)0xFF;
    } else {
        // ---- role A2 ----
        int wv = tid >> 6, lane = tid & 63;
        int pair = (blockIdx.x - KC_GRID - KA1_BLOCKS) * 4 + wv;   // 0..2047
        int b = pair >> 5, g = pair & 31;
        float4 gb = ((const float4*)gt_boxes)[b * GG + g];
        float gx1 = gb.x - gb.z / 2.0f, gy1 = gb.y - gb.w / 2.0f;
        float gx2 = gb.x + gb.z / 2.0f, gy2 = gb.y + gb.w / 2.0f;
        float gar2 = (gx2 - gx1) * (gy2 - gy1);
        const float4* __restrict__ A4 = (const float4*)anchors;
        float bi = -1.0f, bu = 1.0f; int ba = 0;
        // 8732 = 64*136 + 28; 136 = 8*17: a = lane + 64k ascending (tie order kept)
        for (int k0 = 0; k0 < 136; k0 += 8) {
            int a0 = lane + 64 * k0;
            float4 v0 = A4[a0];                   // 8 independent loads in flight
            float4 v1 = A4[a0 + 64];
            float4 v2 = A4[a0 + 128];
            float4 v3 = A4[a0 + 192];
            float4 v4 = A4[a0 + 256];
            float4 v5 = A4[a0 + 320];
            float4 v6 = A4[a0 + 384];
            float4 v7 = A4[a0 + 448];
            iou_upd(v0, a0,       gx1, gy1, gx2, gy2, gar2, bi, bu, ba);
            iou_upd(v1, a0 + 64,  gx1, gy1, gx2, gy2, gar2, bi, bu, ba);
            iou_upd(v2, a0 + 128, gx1, gy1, gx2, gy2, gar2, bi, bu, ba);
            iou_upd(v3, a0 + 192, gx1, gy1, gx2, gy2, gar2, bi, bu, ba);
            iou_upd(v4, a0 + 256, gx1, gy1, gx2, gy2, gar2, bi, bu, ba);
            iou_upd(v5, a0 + 320, gx1, gy1, gx2, gy2, gar2, bi, bu, ba);
            iou_upd(v6, a0 + 384, gx1, gy1, gx2, gy2, gar2, bi, bu, ba);
            iou_upd(v7, a0 + 448, gx1, gy1, gx2, gy2, gar2, bi, bu, ba);
        }
        if (lane < 28) {                          // tail: a = 8704..8731
            int a = 8704 + lane;
            iou_upd(A4[a], a, gx1, gy1, gx2, gy2, gar2, bi, bu, ba);
        }
        // wave butterfly-reduce, lexicographic (iou desc, a asc)
#pragma unroll
        for (int off = 32; off > 0; off >>= 1) {
            float oi = __shfl_down(bi, off);
            float ou = __shfl_down(bu, off);
            int   oa = __shfl_down(ba, off);
            float p1 = oi * bu, p2 = bi * ou;
            bool take = (p1 > p2) || ((p1 == p2) && (oa < ba));
            if (take) { bi = oi; bu = ou; ba = oa; }
        }
        if (lane == 0) bestp[pair] = (unsigned int)ba;
    }
}

// ---------------- Kernel BE: finalize + radix top-k + final reduce, fused ----------------
// One block per image, 1024 threads. Keys/labels live only in LDS. Radix
// pass-1 histogram uses leader-ballot aggregation (one atomic per dominant
// digit per wave-iteration); spread digits fall back to per-lane atomics.
__global__ __launch_bounds__(1024, 4) void kBE(const float* __restrict__ anchors,
    const float* __restrict__ gt_boxes, const int* __restrict__ gt_labels,
    const float* __restrict__ loc_pred, const unsigned char* __restrict__ bestg,
    const unsigned int* __restrict__ bestp, const float* __restrict__ cls_l,
    const float* __restrict__ conf, unsigned int* __restrict__ ticket,
    double* __restrict__ btot_acc, int* __restrict__ np_acc,
    float* __restrict__ out)
{
    int b = blockIdx.x, tid = threadIdx.x, lane = tid & 63;
    __shared__ unsigned int cl[AA];               // 34928 B
    __shared__ unsigned char slab[AA];            // 8732 B
    __shared__ unsigned int hist[256];
    __shared__ float gcx[GG], gcy[GG], gw[GG], gh[GG];
    __shared__ int glab[GG];
    __shared__ unsigned int bp[GG];
    __shared__ double red_d[16], red_p[16];
    __shared__ int red_i[16];
    __shared__ unsigned int red_u[16];
    __shared__ unsigned int sh_prefix, sh_remaining;
    __shared__ int sh_np;
    __shared__ double sh_loc, sh_pc;

    if (tid < GG) {
        float4 gb = ((const float4*)gt_boxes)[b * GG + tid];
        gcx[tid] = gb.x; gcy[tid] = gb.y; gw[tid] = gb.z; gh[tid] = gb.w;
        glab[tid] = gt_labels[b * GG + tid];
        bp[tid] = bestp[b * GG + tid];
    }
    __syncthreads();

    // ---- phase B: labels, loc loss, keys, positive CE ----
    double lsum = 0.0, pc = 0.0; int pcount = 0;
    for (int a = tid; a < AA; a += 1024) {
        int gf = -1;
#pragma unroll
        for (int g = 0; g < GG; ++g)
            if (bp[g] == (unsigned int)a) gf = g; // ascending: largest g wins
        int gsel;
        if (gf >= 0) gsel = gf;
        else {
            unsigned char bg = bestg[b * AA + a];
            gsel = (bg == 0xFF) ? -1 : (int)bg;
        }
        int lab = 0;
        if (gsel >= 0) {
            lab = glab[gsel];                     // labels in 1..C-1 -> positive
            float4 an = ((const float4*)anchors)[a];
            float e0 = (gcx[gsel] - an.x) / an.z;
            float e1 = (gcy[gsel] - an.y) / an.w;
            float e2 = logf(gw[gsel]) - logf(an.z);
            float e3 = logf(gh[gsel]) - logf(an.w);
            float4 lp = ((const float4*)loc_pred)[b * AA + a];
            float d0 = lp.x - e0, d1 = lp.y - e1, d2 = lp.z - e2, d3 = lp.w - e3;
            float t = 0.0f, ad;
            ad = fabsf(d0); t += (ad < 1.0f) ? 0.5f * d0 * d0 : ad - 0.5f;
            ad = fabsf(d1); t += (ad < 1.0f) ? 0.5f * d1 * d1 : ad - 0.5f;
            ad = fabsf(d2); t += (ad < 1.0f) ? 0.5f * d2 * d2 : ad - 0.5f;
            ad = fabsf(d3); t += (ad < 1.0f) ? 0.5f * d3 * d3 : ad - 0.5f;
            lsum += (double)t;
            pcount++;
        }
        slab[a] = (unsigned char)lab;
        float sv = cls_l[b * AA + a];
        if (lab > 0) {
            size_t rowb = ((size_t)(b * AA + a)) * 81;
            pc += (double)(sv + conf[rowb] - conf[rowb + lab]);  // lse - conf[label]
            cl[a] = 0u;                           // positives excluded from mining
        } else {
            cl[a] = __float_as_uint(fmaxf(sv, 0.0f));  // guard tiny negative rounding
        }
    }
#pragma unroll
    for (int off = 32; off > 0; off >>= 1) {
        lsum += __shfl_down(lsum, off);
        pc += __shfl_down(pc, off);
        pcount += __shfl_down(pcount, off);
    }
    if (lane == 0) { red_d[tid >> 6] = lsum; red_p[tid >> 6] = pc; red_i[tid >> 6] = pcount; }
    __syncthreads();
    if (tid == 0) {
        double L = 0.0, C = 0.0; int P = 0;
        for (int w = 0; w < 16; ++w) { L += red_d[w]; C += red_p[w]; P += red_i[w]; }
        sh_loc = L; sh_pc = C; sh_np = P;
        sh_prefix = 0u;
        sh_remaining = (unsigned int)min(3 * P, AA - 1);
    }
    __syncthreads();
    int np_ = sh_np;
    int k = min(3 * np_, AA - 1);                 // num_neg = min(3*num_pos, A-1)

    // ---- phase E: radix-select top-k ----
    double topk = 0.0;
    int p_t_pos = 0;                              // positives inside neg_mask (tie at 0)
    if (k > 0) {
        for (int shift = 24; shift >= 0; shift -= 8) {
            if (tid < 256) hist[tid] = 0u;
            __syncthreads();
            unsigned int mask = (shift == 24) ? 0u : (0xFFFFFFFFu << (shift + 8));
            unsigned int pre = sh_prefix;
#pragma unroll
            for (int it = 0; it < 9; ++it) {      // 9*1024 >= 8732; wave-uniform trips
                int i = tid + it * 1024;
                bool in = (i < AA);
                unsigned int u = in ? cl[i] : 0u;
                bool act = in && ((u & mask) == pre);
                unsigned int d = (u >> shift) & 255u;
                unsigned long long actm = __ballot(act);
                while (actm) {                    // aggregate dominant digits
                    int src = __builtin_ctzll(actm);
                    unsigned int d0 = (unsigned int)__shfl((int)d, src);
                    unsigned long long m = __ballot(act && (d == d0));
                    int c = __popcll(m);
                    if (c < 8) break;             // spread digits -> per-lane fallback
                    if (lane == src) atomicAdd(&hist[d0], (unsigned int)c);
                    actm &= ~m;
                }
                if ((actm >> lane) & 1ull) atomicAdd(&hist[d], 1u);
            }
            __syncthreads();
            if (tid < 64) {                       // wave-parallel digit select
                int l = tid;
                unsigned int h4 = hist[4 * l] + hist[4 * l + 1]
                                + hist[4 * l + 2] + hist[4 * l + 3];
                unsigned int S = h4;              // suffix sum over lane groups
#pragma unroll
                for (int off = 1; off < 64; off <<= 1) {
                    unsigned int o = __shfl_down(S, off);
                    S += (l + off < 64) ? o : 0u;
                }
                unsigned int rem = sh_remaining;
                unsigned long long ball = __ballot(S >= rem);  // lanes 0..L set
                int L = 63 - __clzll(ball);
                if (l == L) {
                    unsigned int rem2 = rem - (S - h4);
                    unsigned int c = 0;
                    for (int dd = 4 * L + 3; dd >= 4 * L; --dd) {
                        c += hist[dd];
                        if (c >= rem2) {
                            sh_prefix = pre | ((unsigned int)dd << shift);
                            sh_remaining = rem2 - (c - hist[dd]);
                            break;
                        }
                    }
                }
            }
            __syncthreads();
        }
        unsigned int vbits = sh_prefix;
        unsigned int myc = 0; double mys = 0.0;
        for (int i = tid; i < AA; i += 1024) {
            unsigned int u = cl[i];
            if (u > vbits) { myc++; mys += (double)__uint_as_float(u); }
        }
#pragma unroll
        for (int off = 32; off > 0; off >>= 1) {
            myc += __shfl_down(myc, off);
            mys += __shfl_down(mys, off);
        }
        if (lane == 0) { red_u[tid >> 6] = myc; red_d[tid >> 6] = mys; }
        __syncthreads();
        if (tid == 0) {
            unsigned int cnt_gt = 0; double sum_gt = 0.0;
            for (int w = 0; w < 16; ++w) { cnt_gt += red_u[w]; sum_gt += red_d[w]; }
            topk = sum_gt + (double)(k - (int)cnt_gt) * (double)__uint_as_float(vbits);
            if (vbits == 0u) {                    // rare tie-at-zero path
                int t = k - (int)cnt_gt, c2 = 0;
                for (int i = 0; i < AA && c2 < t; ++i) {
                    if (cl[i] == 0u) { c2++; if (slab[i] > 0) p_t_pos++; }
                }
            }
        }
    }
    if (tid == 0) {
        int unsampled = AA - np_ - k + p_t_pos;
        double clsb = sh_pc + topk + (double)unsampled * (double)logf(81.0f);
        double myb = sh_loc + clsb;
        atomicAdd(btot_acc, myb);                 // device-scope by default
        atomicAdd(np_acc, np_);
        __threadfence();
        unsigned int t = atomicAdd(ticket, 1u);
        if (t == BB - 1) {                        // last block: all adds happened-before
            double tt = atomicAdd(btot_acc, 0.0); // returns old = full sum
            int nn = atomicAdd(np_acc, 0);
            out[0] = (float)(tt / (double)nn);
        }
    }
}

extern "C" void kernel_launch(void* const* d_in, const int* in_sizes, int n_in,
                              void* d_out, int out_size, void* d_ws, size_t ws_size,
                              hipStream_t stream) {
    (void)in_sizes; (void)n_in; (void)out_size; (void)ws_size;
    const float* loc_pred  = (const float*)d_in[0];
    const float* conf_pred = (const float*)d_in[1];
    const float* anchors   = (const float*)d_in[2];
    const float* gt_boxes  = (const float*)d_in[3];
    const int*   gt_labels = (const int*)d_in[4];

    char* ws = (char*)d_ws;
    unsigned int*  bestp    = (unsigned int*)(ws + 0);
    unsigned char* bestg    = (unsigned char*)(ws + 8192);
    float*         cls_l    = (float*)(ws + 567040);
    unsigned int*  ticket   = (unsigned int*)(ws + 2802432);
    double*        btot_acc = (double*)(ws + 2802440);
    int*           np_acc   = (int*)(ws + 2802448);

    kAC<<<TOT_BLOCKS, 256, 0, stream>>>(anchors, gt_boxes, conf_pred,
        bestg, bestp, cls_l, ticket, btot_acc, np_acc);
    kBE<<<BB, 1024, 0, stream>>>(anchors, gt_boxes, gt_labels, loc_pred,
        bestg, bestp, cls_l, conf_pred, ticket, btot_acc, np_acc, (float*)d_out);
}